// Round 1
// baseline (497.742 us; speedup 1.0000x reference)
//
#include <hip/hip_runtime.h>
#include <stdint.h>

#define FP8_MAX 448.0f
#define TOKENS  8192
#define IDIM    4096
#define ODIM    4096

typedef float f32x4 __attribute__((ext_vector_type(4)));

__device__ __forceinline__ void async_copy16(const uint8_t* g, uint8_t* l) {
  __builtin_amdgcn_global_load_lds((const __attribute__((address_space(1))) void*)g,
                                   (__attribute__((address_space(3))) void*)l,
                                   16, 0, 0);
}

// ---------------- per-token activation quantization ----------------
// one block per token row; 256 threads x 16 elems = 4096
__global__ __launch_bounds__(256) void quant_x_kernel(
    const float* __restrict__ x, uint8_t* __restrict__ xq, float* __restrict__ xsc) {
  const int row = blockIdx.x;
  const int tid = threadIdx.x;
  const float* xr = x + (size_t)row * IDIM;

  float4 v[4];
  float amax = 0.0f;
  #pragma unroll
  for (int k = 0; k < 4; k++) {
    v[k] = ((const float4*)xr)[tid + k * 256];
    amax = fmaxf(amax, fmaxf(fmaxf(fabsf(v[k].x), fabsf(v[k].y)),
                             fmaxf(fabsf(v[k].z), fabsf(v[k].w))));
  }
  #pragma unroll
  for (int off = 32; off > 0; off >>= 1)
    amax = fmaxf(amax, __shfl_xor(amax, off, 64));

  __shared__ float smax[4];
  if ((tid & 63) == 0) smax[tid >> 6] = amax;
  __syncthreads();
  amax = fmaxf(fmaxf(smax[0], smax[1]), fmaxf(smax[2], smax[3]));
  amax = fmaxf(amax, 1e-12f);
  const float scale = amax / FP8_MAX;   // matches ref: amax/448 in f32
  if (tid == 0) xsc[row] = scale;

  uint32_t* out = (uint32_t*)(xq + (size_t)row * IDIM);
  #pragma unroll
  for (int k = 0; k < 4; k++) {
    // exact f32 divide to match reference rounding, then RNE fp8 cast
    float a = v[k].x / scale, b = v[k].y / scale;
    float c = v[k].z / scale, d = v[k].w / scale;
    int p = __builtin_amdgcn_cvt_pk_fp8_f32(a, b, 0, false);
    p = __builtin_amdgcn_cvt_pk_fp8_f32(c, d, p, true);
    out[tid + k * 256] = (uint32_t)p;
  }
}

// ---------------- weight f32 -> fp8 bytes (exact: values are fp8-valued) ----------------
__global__ __launch_bounds__(256) void conv_w_kernel(
    const float* __restrict__ w, uint8_t* __restrict__ wq) {
  const size_t base = (size_t)blockIdx.x * 4096;
  const int tid = threadIdx.x;
  const float4* wp = (const float4*)(w + base);
  uint32_t* out = (uint32_t*)(wq + base);
  #pragma unroll
  for (int k = 0; k < 4; k++) {
    float4 v = wp[tid + k * 256];
    int p = __builtin_amdgcn_cvt_pk_fp8_f32(v.x, v.y, 0, false);
    p = __builtin_amdgcn_cvt_pk_fp8_f32(v.z, v.w, p, true);
    out[tid + k * 256] = (uint32_t)p;
  }
}

// ---------------- fp8 block-scaled GEMM ----------------
// y[t][o] = x_scale[t] * sum_kb wsi[o/128][kb] * sum_{k in kb} xq[t][k]*wq[o][k]
// 128x128 tile per block (256 thr = 4 waves, each wave 64x64 via 4x4 16x16 frags), BK=128.
__global__ __launch_bounds__(256) void gemm_fp8_kernel(
    const uint8_t* __restrict__ xq, const uint8_t* __restrict__ wq,
    const float* __restrict__ xsc, const float* __restrict__ wsi,
    float* __restrict__ y) {
  __shared__ uint8_t As[128 * 128];
  __shared__ uint8_t Bs[128 * 128];

  const int tid  = threadIdx.x;
  const int bo   = blockIdx.x & 31;   // 32 o-tiles
  const int bt   = blockIdx.x >> 5;   // 64 t-tiles
  const int t0   = bt << 7;
  const int o0   = bo << 7;
  const int lane = tid & 63;
  const int wave = tid >> 6;
  const int wr   = (wave >> 1) << 6;  // wave token offset in tile
  const int wc   = (wave & 1) << 6;   // wave output offset in tile
  const int ln   = lane & 15;
  const int quad = lane >> 4;

  // Staging: LDS 16B-slot j holds global (row=j>>3, chunk=(j&7)^(row&7)).
  // Swizzle lives in the global source address; LDS dst stays lane-contiguous.
  const int rb  = tid >> 3;                          // row within 32-row group
  const int cs  = ((tid & 7) ^ (rb & 7)) << 4;       // swizzled byte offset in row
  const int lds = tid << 4;

  f32x4 outer[4][4];
  #pragma unroll
  for (int i = 0; i < 4; i++)
    #pragma unroll
    for (int j = 0; j < 4; j++)
      outer[i][j] = (f32x4)(0.0f);

  const float* wsrow = wsi + bo * 32;  // weight_scale_inv[bo][*]

  for (int kb = 0; kb < 32; kb++) {
    const int k0 = kb << 7;
    #pragma unroll
    for (int u = 0; u < 4; u++) {
      async_copy16(xq + ((size_t)(t0 + u * 32 + rb) << 12) + (k0 + cs),
                   As + u * 4096 + lds);
      async_copy16(wq + ((size_t)(o0 + u * 32 + rb) << 12) + (k0 + cs),
                   Bs + u * 4096 + lds);
    }
    __syncthreads();  // compiler emits vmcnt(0) drain for global_load_lds

    f32x4 inner[4][4];
    #pragma unroll
    for (int i = 0; i < 4; i++)
      #pragma unroll
      for (int j = 0; j < 4; j++)
        inner[i][j] = (f32x4)(0.0f);

    #pragma unroll
    for (int ks = 0; ks < 4; ks++) {
      const int ch = ks * 2 + (quad >> 1);   // 16B chunk index in row
      const int b8 = (quad & 1) << 3;        // byte offset within chunk
      long a[4], b[4];
      #pragma unroll
      for (int i = 0; i < 4; i++) {
        const int row = wr + i * 16 + ln;
        a[i] = *(const long*)(As + row * 128 + ((ch ^ (row & 7)) << 4) + b8);
      }
      #pragma unroll
      for (int j = 0; j < 4; j++) {
        const int row = wc + j * 16 + ln;
        b[j] = *(const long*)(Bs + row * 128 + ((ch ^ (row & 7)) << 4) + b8);
      }
      #pragma unroll
      for (int i = 0; i < 4; i++)
        #pragma unroll
        for (int j = 0; j < 4; j++)
          inner[i][j] = __builtin_amdgcn_mfma_f32_16x16x32_fp8_fp8(
              a[i], b[j], inner[i][j], 0, 0, 0);
    }

    const float s = wsrow[kb];               // wave-uniform -> s_load
    #pragma unroll
    for (int i = 0; i < 4; i++)
      #pragma unroll
      for (int j = 0; j < 4; j++)
        outer[i][j] += s * inner[i][j];
    __syncthreads();
  }

  // epilogue: C/D frag (row = quad*4+reg -> token, col = ln -> output), * x_scale[t]
  #pragma unroll
  for (int i = 0; i < 4; i++) {
    #pragma unroll
    for (int r = 0; r < 4; r++) {
      const int t = t0 + wr + i * 16 + quad * 4 + r;
      const float sc = xsc[t];
      float* yp = y + ((size_t)t << 12) + o0 + wc + ln;
      #pragma unroll
      for (int j = 0; j < 4; j++)
        yp[j * 16] = outer[i][j][r] * sc;
    }
  }
}

extern "C" void kernel_launch(void* const* d_in, const int* in_sizes, int n_in,
                              void* d_out, int out_size, void* d_ws, size_t ws_size,
                              hipStream_t stream) {
  const float* x   = (const float*)d_in[0];   // [8192,4096] f32
  const float* w   = (const float*)d_in[1];   // [4096,4096] f32 (fp8-valued)
  const float* wsi = (const float*)d_in[2];   // [32,32] f32
  float* y = (float*)d_out;                   // [8192,4096] f32

  // workspace layout: 33.55MB xq + 16.78MB wq + 32KB xsc = 50.4 MB
  uint8_t* xq = (uint8_t*)d_ws;
  uint8_t* wq = xq + (size_t)TOKENS * IDIM;
  float*  xsc = (float*)(wq + (size_t)ODIM * IDIM);

  quant_x_kernel<<<TOKENS, 256, 0, stream>>>(x, xq, xsc);
  conv_w_kernel<<<((size_t)ODIM * IDIM) / 4096, 256, 0, stream>>>(w, wq);
  gemm_fp8_kernel<<<(TOKENS / 128) * (ODIM / 128), 256, 0, stream>>>(xq, wq, xsc, wsi, y);
}

// Round 4
// 424.878 us; speedup vs baseline: 1.1715x; 1.1715x over previous
//
#include <hip/hip_runtime.h>
#include <stdint.h>

#define FP8_MAX 448.0f
#define TOKENS  8192
#define IDIM    4096
#define ODIM    4096

typedef float f32x4 __attribute__((ext_vector_type(4)));
typedef int   i32x4 __attribute__((ext_vector_type(4)));
typedef int   i32x8 __attribute__((ext_vector_type(8)));

__device__ __forceinline__ void async_copy16(const uint8_t* g, uint8_t* l) {
  __builtin_amdgcn_global_load_lds((const __attribute__((address_space(1))) void*)g,
                                   (__attribute__((address_space(3))) void*)l,
                                   16, 0, 0);
}

// ---------------- fused prep: per-token x quant (blocks 0..8191) + w f32->fp8 (blocks 8192..12287) ----------------
__global__ __launch_bounds__(256) void prep_kernel(
    const float* __restrict__ x, const float* __restrict__ w,
    uint8_t* __restrict__ xq, uint8_t* __restrict__ wq, float* __restrict__ xsc) {
  const int tid = threadIdx.x;
  if (blockIdx.x < TOKENS) {
    const int row = blockIdx.x;
    const f32x4* xr = (const f32x4*)(x + (size_t)row * IDIM);

    f32x4 v[4];
    float amax = 0.0f;
    #pragma unroll
    for (int k = 0; k < 4; k++) {
      v[k] = xr[tid + k * 256];
      amax = fmaxf(amax, fmaxf(fmaxf(fabsf(v[k].x), fabsf(v[k].y)),
                               fmaxf(fabsf(v[k].z), fabsf(v[k].w))));
    }
    #pragma unroll
    for (int off = 32; off > 0; off >>= 1)
      amax = fmaxf(amax, __shfl_xor(amax, off, 64));

    __shared__ float smax[4];
    if ((tid & 63) == 0) smax[tid >> 6] = amax;
    __syncthreads();
    amax = fmaxf(fmaxf(smax[0], smax[1]), fmaxf(smax[2], smax[3]));
    amax = fmaxf(amax, 1e-12f);
    const float scale = amax / FP8_MAX;   // matches ref: amax/448 in f32
    if (tid == 0) xsc[row] = scale;

    uint32_t* out = (uint32_t*)(xq + (size_t)row * IDIM);
    #pragma unroll
    for (int k = 0; k < 4; k++) {
      // exact f32 divide to match reference rounding, then RNE fp8 cast
      float a = v[k].x / scale, b = v[k].y / scale;
      float c = v[k].z / scale, d = v[k].w / scale;
      int p = __builtin_amdgcn_cvt_pk_fp8_f32(a, b, 0, false);
      p = __builtin_amdgcn_cvt_pk_fp8_f32(c, d, p, true);
      out[tid + k * 256] = (uint32_t)p;
    }
  } else {
    const size_t base = (size_t)(blockIdx.x - TOKENS) * 4096;
    const f32x4* wp = (const f32x4*)(w + base);
    uint32_t* out = (uint32_t*)(wq + base);
    #pragma unroll
    for (int k = 0; k < 4; k++) {
      f32x4 v = wp[tid + k * 256];
      int p = __builtin_amdgcn_cvt_pk_fp8_f32(v.x, v.y, 0, false);
      p = __builtin_amdgcn_cvt_pk_fp8_f32(v.z, v.w, p, true);
      out[tid + k * 256] = (uint32_t)p;
    }
  }
}

// ---------------- fp8 block-scaled GEMM (MX-scaled MFMA, identity e8m0 scales) ----------------
// y[t][o] = x_scale[t] * sum_kb wsi[o/128][kb] * sum_{k in kb} xq[t][k]*wq[o][k]
// 128x128 tile per block (256 thr = 4 waves, each wave 64x64 via 4x4 16x16 frags), BK=128.
// One mfma_scale_f32_16x16x128_f8f6f4 per (frag, kb): K=128 in one instr at 2x fp8 rate.
__global__ __launch_bounds__(256) void gemm_fp8_kernel(
    const uint8_t* __restrict__ xq, const uint8_t* __restrict__ wq,
    const float* __restrict__ xsc, const float* __restrict__ wsi,
    float* __restrict__ y) {
  __shared__ __align__(16) uint8_t As[128 * 128];
  __shared__ __align__(16) uint8_t Bs[128 * 128];

  const int tid  = threadIdx.x;
  const int bo   = blockIdx.x & 31;   // 32 o-tiles
  const int bt   = blockIdx.x >> 5;   // 64 t-tiles
  const int t0   = bt << 7;
  const int o0   = bo << 7;
  const int lane = tid & 63;
  const int wave = tid >> 6;
  const int wr   = (wave >> 1) << 6;  // wave token offset in tile
  const int wc   = (wave & 1) << 6;   // wave output offset in tile
  const int ln   = lane & 15;
  const int quad = lane >> 4;

  // Staging: LDS 16B-slot j holds global (row=j>>3, chunk=(j&7)^(row&7)).
  // Swizzle lives in the global source address; LDS dst stays lane-contiguous.
  const int rb  = tid >> 3;                          // row within 32-row group
  const int cs  = ((tid & 7) ^ (rb & 7)) << 4;       // swizzled byte offset in row
  const int lds = tid << 4;

  // A-operand layout for 16x16x128 f8f6f4: row = lane&15, k = quad*32 + byte(0..31)
  // -> lane reads 16B chunks (2*quad) and (2*quad+1) of its row (XOR-swizzled).
  const int c0 = quad << 1;
  int aoff[4][2], boff[4][2];
  #pragma unroll
  for (int i = 0; i < 4; i++) {
    const int ra = wr + i * 16 + ln;
    const int sa = ra & 7;
    aoff[i][0] = ra * 128 + ((c0 ^ sa) << 4);
    aoff[i][1] = ra * 128 + (((c0 + 1) ^ sa) << 4);
    const int rb2 = wc + i * 16 + ln;
    const int sb = rb2 & 7;
    boff[i][0] = rb2 * 128 + ((c0 ^ sb) << 4);
    boff[i][1] = rb2 * 128 + (((c0 + 1) ^ sb) << 4);
  }

  f32x4 outer[4][4];
  #pragma unroll
  for (int i = 0; i < 4; i++)
    #pragma unroll
    for (int j = 0; j < 4; j++)
      outer[i][j] = (f32x4)(0.0f);

  const float* wsrow = wsi + bo * 32;     // weight_scale_inv[bo][*]
  const int ident = 0x7f7f7f7f;           // e8m0 identity scale (2^0) in all bytes
  const f32x4 zero4 = (f32x4)(0.0f);

  for (int kb = 0; kb < 32; kb++) {
    const int k0 = kb << 7;
    #pragma unroll
    for (int u = 0; u < 4; u++) {
      async_copy16(xq + ((size_t)(t0 + u * 32 + rb) << 12) + (k0 + cs),
                   As + u * 4096 + lds);
      async_copy16(wq + ((size_t)(o0 + u * 32 + rb) << 12) + (k0 + cs),
                   Bs + u * 4096 + lds);
    }
    __syncthreads();  // compiler emits vmcnt(0) drain for global_load_lds

    i32x8 a[4], b[4];
    #pragma unroll
    for (int i = 0; i < 4; i++) {
      i32x4 lo = *(const i32x4*)(As + aoff[i][0]);
      i32x4 hi = *(const i32x4*)(As + aoff[i][1]);
      a[i] = __builtin_shufflevector(lo, hi, 0, 1, 2, 3, 4, 5, 6, 7);
    }
    #pragma unroll
    for (int j = 0; j < 4; j++) {
      i32x4 lo = *(const i32x4*)(Bs + boff[j][0]);
      i32x4 hi = *(const i32x4*)(Bs + boff[j][1]);
      b[j] = __builtin_shufflevector(lo, hi, 0, 1, 2, 3, 4, 5, 6, 7);
    }

    const float s = wsrow[kb];            // wave-uniform -> scalar load
    #pragma unroll
    for (int i = 0; i < 4; i++)
      #pragma unroll
      for (int j = 0; j < 4; j++) {
        f32x4 t = __builtin_amdgcn_mfma_scale_f32_16x16x128_f8f6f4(
            a[i], b[j], zero4, 0, 0, 0, ident, 0, ident);
        outer[i][j] += s * t;
      }
    __syncthreads();
  }

  // epilogue: C/D frag (row = quad*4+reg -> token, col = ln -> output), * x_scale[t]
  #pragma unroll
  for (int i = 0; i < 4; i++) {
    #pragma unroll
    for (int r = 0; r < 4; r++) {
      const int t = t0 + wr + i * 16 + quad * 4 + r;
      const float sc = xsc[t];
      float* yp = y + ((size_t)t << 12) + o0 + wc + ln;
      #pragma unroll
      for (int j = 0; j < 4; j++)
        yp[j * 16] = outer[i][j][r] * sc;
    }
  }
}

extern "C" void kernel_launch(void* const* d_in, const int* in_sizes, int n_in,
                              void* d_out, int out_size, void* d_ws, size_t ws_size,
                              hipStream_t stream) {
  const float* x   = (const float*)d_in[0];   // [8192,4096] f32
  const float* w   = (const float*)d_in[1];   // [4096,4096] f32 (fp8-valued)
  const float* wsi = (const float*)d_in[2];   // [32,32] f32
  float* y = (float*)d_out;                   // [8192,4096] f32

  // workspace layout: 33.55MB xq + 16.78MB wq + 32KB xsc = 50.4 MB
  uint8_t* xq = (uint8_t*)d_ws;
  uint8_t* wq = xq + (size_t)TOKENS * IDIM;
  float*  xsc = (float*)(wq + (size_t)ODIM * IDIM);

  prep_kernel<<<TOKENS + ((size_t)ODIM * IDIM) / 4096, 256, 0, stream>>>(x, w, xq, wq, xsc);
  gemm_fp8_kernel<<<(TOKENS / 128) * (ODIM / 128), 256, 0, stream>>>(xq, wq, xsc, wsi, y);
}